// Round 2
// baseline (291.383 us; speedup 1.0000x reference)
//
#include <hip/hip_runtime.h>

#define NQ   2048
#define NB   8
#define ROWS 8                       // i-rows per block
#define TPB  256
#define NBLK (NB * (NQ / ROWS))      // 2048 blocks

__global__ __launch_bounds__(TPB, 4) void idla_main(
        const float* __restrict__ preds,
        const float* __restrict__ targets,
        const float* __restrict__ adj,
        double* __restrict__ ws,
        float* __restrict__ out) {
    __shared__ float red_sq[TPB / 64], red_ad[TPB / 64];

    const int nbpb = NQ / ROWS;                // 256
    const int b    = blockIdx.x / nbpb;
    const int i0   = (blockIdx.x % nbpb) * ROWS;
    const int tid  = threadIdx.x;

    const float* pb   = preds   + (size_t)b * NQ * 3;
    const float* tb   = targets + (size_t)b * NQ * 3;
    const float* adjb = adj     + (size_t)b * NQ * NQ;

    // Each thread owns 8 fixed j-columns: {tid*4..+3} and {1024+tid*4..+3}.
    // Load their 3D coords (preds+targets) into registers once. 48B-aligned.
    float jpx[2][4], jpy[2][4], jpz[2][4];
    float jtx[2][4], jty[2][4], jtz[2][4];
    #pragma unroll
    for (int g = 0; g < 2; g++) {
        const int j = g * (NQ / 2) + tid * 4;
        const float* p = pb + (size_t)j * 3;
        float4 a = *(const float4*)(p);
        float4 c = *(const float4*)(p + 4);
        float4 e = *(const float4*)(p + 8);
        jpx[g][0] = a.x; jpy[g][0] = a.y; jpz[g][0] = a.z;
        jpx[g][1] = a.w; jpy[g][1] = c.x; jpz[g][1] = c.y;
        jpx[g][2] = c.z; jpy[g][2] = c.w; jpz[g][2] = e.x;
        jpx[g][3] = e.y; jpy[g][3] = e.z; jpz[g][3] = e.w;
        const float* t = tb + (size_t)j * 3;
        float4 f = *(const float4*)(t);
        float4 h = *(const float4*)(t + 4);
        float4 k = *(const float4*)(t + 8);
        jtx[g][0] = f.x; jty[g][0] = f.y; jtz[g][0] = f.z;
        jtx[g][1] = f.w; jty[g][1] = h.x; jtz[g][1] = h.y;
        jtx[g][2] = h.z; jty[g][2] = h.w; jtz[g][2] = k.x;
        jtx[g][3] = k.y; jty[g][3] = k.z; jtz[g][3] = k.w;
    }

    float acc_sq = 0.0f;
    float acc_ad = 0.0f;

    #pragma unroll
    for (int ii = 0; ii < ROWS; ii++) {
        const int i = i0 + ii;
        // Wave-uniform addresses -> scalar loads, broadcast to all lanes.
        const float pix = pb[i * 3 + 0], piy = pb[i * 3 + 1], piz = pb[i * 3 + 2];
        const float tix = tb[i * 3 + 0], tiy = tb[i * 3 + 1], tiz = tb[i * 3 + 2];
        #pragma unroll
        for (int g = 0; g < 2; g++) {
            const float4 a4 =
                *(const float4*)&adjb[(size_t)i * NQ + g * (NQ / 2) + tid * 4];
            const float av[4] = {a4.x, a4.y, a4.z, a4.w};
            #pragma unroll
            for (int jj = 0; jj < 4; jj++) {
                float dx = pix - jpx[g][jj];
                float dy = piy - jpy[g][jj];
                float dz = piz - jpz[g][jj];
                float dp = __builtin_amdgcn_sqrtf(fmaf(dx, dx, fmaf(dy, dy, dz * dz)));
                float ex = tix - jtx[g][jj];
                float ey = tiy - jty[g][jj];
                float ez = tiz - jtz[g][jj];
                float dt = __builtin_amdgcn_sqrtf(fmaf(ex, ex, fmaf(ey, ey, ez * ez)));
                float d = (dp - dt) * av[jj];
                acc_sq = fmaf(d, d, acc_sq);
                acc_ad += av[jj];
            }
        }
    }

    // Wave64 shuffle reduction, then cross-wave via tiny LDS.
    #pragma unroll
    for (int off = 32; off > 0; off >>= 1) {
        acc_sq += __shfl_down(acc_sq, off, 64);
        acc_ad += __shfl_down(acc_ad, off, 64);
    }
    const int wave = tid >> 6;
    if ((tid & 63) == 0) { red_sq[wave] = acc_sq; red_ad[wave] = acc_ad; }
    __syncthreads();
    if (tid == 0) {
        float s_sq = 0.0f, s_ad = 0.0f;
        #pragma unroll
        for (int w = 0; w < TPB / 64; w++) { s_sq += red_sq[w]; s_ad += red_ad[w]; }
        atomicAdd(&ws[0], (double)s_sq);
        atomicAdd(&ws[1], (double)s_ad);
        __threadfence();  // make the adds visible before signaling done
        unsigned* cnt = (unsigned*)(ws + 2);
        unsigned done = atomicAdd(cnt, 1u);
        if (done == NBLK - 1) {
            // Last block: read via atomic RMW (device-scope coherent) and finalize.
            double sq = atomicAdd(&ws[0], 0.0);
            double ad = atomicAdd(&ws[1], 0.0);
            out[0] = (float)(sq / ad);
        }
    }
}

extern "C" void kernel_launch(void* const* d_in, const int* in_sizes, int n_in,
                              void* d_out, int out_size, void* d_ws, size_t ws_size,
                              hipStream_t stream) {
    const float* preds   = (const float*)d_in[0];
    const float* targets = (const float*)d_in[1];
    const float* adj     = (const float*)d_in[2];
    double* ws  = (double*)d_ws;
    float*  out = (float*)d_out;

    // ws[0]=sum_sq (double), ws[1]=sum_adj (double), ws+2: unsigned counter
    hipMemsetAsync(ws, 0, 24, stream);
    hipLaunchKernelGGL(idla_main, dim3(NBLK), dim3(TPB), 0, stream,
                       preds, targets, adj, ws, out);
}

// Round 3
// 246.293 us; speedup vs baseline: 1.1831x; 1.1831x over previous
//
#include <hip/hip_runtime.h>

#define NQ    2048
#define NB    8
#define ROWS  16                     // i-rows per block
#define TPB   256
#define NBLK  (NB * (NQ / ROWS))     // 1024 blocks
#define STEPS (ROWS * 2)             // (row, half) pairs: 32 adj loads/thread
#define PIPE  8                      // outstanding adj loads per thread

__global__ __launch_bounds__(TPB, 4) void idla_main(
        const float* __restrict__ preds,
        const float* __restrict__ targets,
        const float* __restrict__ adj,
        double* __restrict__ ws,
        float* __restrict__ out) {
    __shared__ float red_sq[TPB / 64], red_ad[TPB / 64];

    const int nbpb = NQ / ROWS;                // 128
    const int b    = blockIdx.x / nbpb;
    const int i0   = (blockIdx.x % nbpb) * ROWS;
    const int tid  = threadIdx.x;

    const float* pb   = preds   + (size_t)b * NQ * 3;
    const float* tb   = targets + (size_t)b * NQ * 3;
    const float* adjb = adj     + (size_t)b * NQ * NQ;

    // ---- j-coords: each thread owns 8 fixed columns, in registers ----
    float jpx[2][4], jpy[2][4], jpz[2][4];
    float jtx[2][4], jty[2][4], jtz[2][4];
    #pragma unroll
    for (int g = 0; g < 2; g++) {
        const int j = g * (NQ / 2) + tid * 4;
        const float* p = pb + (size_t)j * 3;
        float4 a = *(const float4*)(p);
        float4 c = *(const float4*)(p + 4);
        float4 e = *(const float4*)(p + 8);
        jpx[g][0] = a.x; jpy[g][0] = a.y; jpz[g][0] = a.z;
        jpx[g][1] = a.w; jpy[g][1] = c.x; jpz[g][1] = c.y;
        jpx[g][2] = c.z; jpy[g][2] = c.w; jpz[g][2] = e.x;
        jpx[g][3] = e.y; jpy[g][3] = e.z; jpz[g][3] = e.w;
        const float* t = tb + (size_t)j * 3;
        float4 f = *(const float4*)(t);
        float4 h = *(const float4*)(t + 4);
        float4 k = *(const float4*)(t + 8);
        jtx[g][0] = f.x; jty[g][0] = f.y; jtz[g][0] = f.z;
        jtx[g][1] = f.w; jty[g][1] = h.x; jtz[g][1] = h.y;
        jtx[g][2] = h.z; jty[g][2] = h.w; jtz[g][2] = k.x;
        jtx[g][3] = k.y; jty[g][3] = k.z; jtz[g][3] = k.w;
    }

    // ---- i-coords: wave-uniform -> SGPRs, hoisted out of the hot loop ----
    float ipx[ROWS], ipy[ROWS], ipz[ROWS], itx[ROWS], ity[ROWS], itz[ROWS];
    #pragma unroll
    for (int ii = 0; ii < ROWS; ii++) {
        const int i = i0 + ii;
        ipx[ii] = pb[i * 3 + 0]; ipy[ii] = pb[i * 3 + 1]; ipz[ii] = pb[i * 3 + 2];
        itx[ii] = tb[i * 3 + 0]; ity[ii] = tb[i * 3 + 1]; itz[ii] = tb[i * 3 + 2];
    }

    float acc_sq = 0.0f;
    float acc_ad = 0.0f;

    // ---- software-pipelined adj stream: PIPE loads in flight per thread ----
    // step r -> row (r>>1), half (r&1); address = abase + row*NQ + half*NQ/2
    const float* abase = adjb + (size_t)i0 * NQ + (size_t)tid * 4;

    float4 buf[PIPE];
    #pragma unroll
    for (int k = 0; k < PIPE; k++)
        buf[k] = *(const float4*)(abase + (size_t)(k >> 1) * NQ + (k & 1) * (NQ / 2));

    #pragma unroll
    for (int r = 0; r < STEPS; r++) {
        const float4 a4 = buf[r % PIPE];
        const int rn = r + PIPE;
        if (rn < STEPS)
            buf[r % PIPE] =
                *(const float4*)(abase + (size_t)(rn >> 1) * NQ + (rn & 1) * (NQ / 2));

        const int ii = r >> 1;
        const int g  = r & 1;
        const float pix = ipx[ii], piy = ipy[ii], piz = ipz[ii];
        const float tix = itx[ii], tiy = ity[ii], tiz = itz[ii];
        const float av[4] = {a4.x, a4.y, a4.z, a4.w};
        #pragma unroll
        for (int jj = 0; jj < 4; jj++) {
            float dx = pix - jpx[g][jj];
            float dy = piy - jpy[g][jj];
            float dz = piz - jpz[g][jj];
            float sa = fmaf(dx, dx, fmaf(dy, dy, dz * dz));   // |p_i - p_j|^2
            float ex = tix - jtx[g][jj];
            float ey = tiy - jty[g][jj];
            float ez = tiz - jtz[g][jj];
            float sb = fmaf(ex, ex, fmaf(ey, ey, ez * ez));   // |t_i - t_j|^2
            // (sqrt(sa)-sqrt(sb))^2 = sa + sb - 2*sqrt(sa*sb)  [one sqrt]
            float s  = __builtin_amdgcn_sqrtf(sa * sb);
            float t  = fmaf(-2.0f, s, sa + sb);
            acc_sq = fmaf(av[jj], t, acc_sq);
            acc_ad += av[jj];
        }
    }

    // ---- wave64 shuffle reduction, then cross-wave via tiny LDS ----
    #pragma unroll
    for (int off = 32; off > 0; off >>= 1) {
        acc_sq += __shfl_down(acc_sq, off, 64);
        acc_ad += __shfl_down(acc_ad, off, 64);
    }
    const int wave = tid >> 6;
    if ((tid & 63) == 0) { red_sq[wave] = acc_sq; red_ad[wave] = acc_ad; }
    __syncthreads();
    if (tid == 0) {
        float s_sq = 0.0f, s_ad = 0.0f;
        #pragma unroll
        for (int w = 0; w < TPB / 64; w++) { s_sq += red_sq[w]; s_ad += red_ad[w]; }
        atomicAdd(&ws[0], (double)s_sq);
        atomicAdd(&ws[1], (double)s_ad);
        __threadfence();
        unsigned* cnt = (unsigned*)(ws + 2);
        unsigned done = atomicAdd(cnt, 1u);
        if (done == NBLK - 1) {
            double sq = atomicAdd(&ws[0], 0.0);
            double ad = atomicAdd(&ws[1], 0.0);
            out[0] = (float)(sq / ad);
        }
    }
}

extern "C" void kernel_launch(void* const* d_in, const int* in_sizes, int n_in,
                              void* d_out, int out_size, void* d_ws, size_t ws_size,
                              hipStream_t stream) {
    const float* preds   = (const float*)d_in[0];
    const float* targets = (const float*)d_in[1];
    const float* adj     = (const float*)d_in[2];
    double* ws  = (double*)d_ws;
    float*  out = (float*)d_out;

    // ws[0]=sum_sq, ws[1]=sum_adj (doubles), ws+2: unsigned done-counter
    hipMemsetAsync(ws, 0, 24, stream);
    hipLaunchKernelGGL(idla_main, dim3(NBLK), dim3(TPB), 0, stream,
                       preds, targets, adj, ws, out);
}